// Round 6
// baseline (441.109 us; speedup 1.0000x reference)
//
#include <hip/hip_runtime.h>
#include <hip/hip_bf16.h>
#include <cstdint>

// Problem constants
static constexpr int Bc  = 4;
static constexpr int Sc  = 8192;
static constexpr int Dc  = 1024;
static constexpr int Hc  = 16;
static constexpr int BHc = Bc * Hc;   // 64
static constexpr int Mc  = Bc * Sc;   // 32768
static constexpr int N3c = 3 * Dc;    // 3072
static constexpr float EPSc = 1e-6f;

using bf16x8 = __attribute__((ext_vector_type(8))) __bf16;
using f32x4  = __attribute__((ext_vector_type(4))) float;

__device__ __forceinline__ ushort f2bf(float f) {
  union { float f; uint32_t u; } v; v.f = f;
  uint32_t u = v.u;
  return (ushort)((u + 0x7fffu + ((u >> 16) & 1u)) >> 16);  // RNE
}
__device__ __forceinline__ float bf2f(ushort h) {
  union { uint32_t u; float f; } v; v.u = ((uint32_t)h) << 16;
  return v.f;
}

typedef const __attribute__((address_space(1))) unsigned int* gas_u32p;
typedef __attribute__((address_space(3))) unsigned int* las_u32p;
__device__ __forceinline__ void gld_lds16(const void* g, void* l) {
  __builtin_amdgcn_global_load_lds((gas_u32p)g, (las_u32p)l, 16, 0, 0);
}

#define FENCE asm volatile("" ::: "memory")
#define BARF  do { FENCE; __builtin_amdgcn_s_barrier(); FENCE; } while (0)

// ---------------------------------------------------------------- kernel 0: fp32 -> bf16 convert (x)
__global__ __launch_bounds__(256) void cvt_bf16_k(const float* __restrict__ src,
                                                  ushort* __restrict__ dst, int n4) {
  for (int i = blockIdx.x * 256 + threadIdx.x; i < n4; i += gridDim.x * 256) {
    float4 v = reinterpret_cast<const float4*>(src)[i];
    ushort4 o; o.x = f2bf(v.x); o.y = f2bf(v.y); o.z = f2bf(v.z); o.w = f2bf(v.w);
    reinterpret_cast<ushort4*>(dst)[i] = o;
  }
}

// ---------------------------------------------------------------- kernel 1: weight fold
// rows 0..1023: W_p@W_Q, bias=W_p b_Q+b_p; 1024..2047: W_p@W_K likewise; 2048..3071: W_V, b_V.
__global__ __launch_bounds__(256) void fold_k(const float* __restrict__ Wq,
                                              const float* __restrict__ Wp,
                                              const float* __restrict__ bq,
                                              const float* __restrict__ bp,
                                              ushort* __restrict__ W3b,
                                              float* __restrict__ bias3) {
  const int bx = blockIdx.x;          // 0..47
  const int p = bx >> 4, h = bx & 15;
  const int t = threadIdx.x;
  if (p == 2) {
    const int base = 2048 + h * 64;
    for (int li = t; li < 64 * 256; li += 256) {
      int r = li >> 8, c4 = (li & 255) * 4;
      float4 v = *reinterpret_cast<const float4*>(&Wq[(size_t)(base + r) * 1024 + c4]);
      ushort4 o; o.x = f2bf(v.x); o.y = f2bf(v.y); o.z = f2bf(v.z); o.w = f2bf(v.w);
      *reinterpret_cast<ushort4*>(&W3b[(size_t)(base + r) * 1024 + c4]) = o;
    }
    if (t < 64) bias3[base + t] = bq[base + t];
    return;
  }
  __shared__ ushort Ws[64 * 64];    // [a][hd]
  __shared__ ushort Tq[256 * 64];   // [d][hd]
  const int rbase = p * 1024 + h * 64;
  for (int li = t; li < 64 * 16; li += 256) {
    int a = li >> 4, h4 = (li & 15) * 4;
    float4 v = *reinterpret_cast<const float4*>(&Wp[a * 64 + h4]);
    ushort4 o; o.x = f2bf(v.x); o.y = f2bf(v.y); o.z = f2bf(v.z); o.w = f2bf(v.w);
    *reinterpret_cast<ushort4*>(&Ws[a * 64 + h4]) = o;
  }
  if (t < 64) {
    float s = bp[t];
    for (int hd = 0; hd < 64; ++hd) s += Wp[t * 64 + hd] * bq[rbase + hd];
    bias3[rbase + t] = s;
  }
  const int w = t >> 6, lane = t & 63, lr = lane & 15, kg = lane >> 4;
  for (int dt = 0; dt < 4; ++dt) {
    __syncthreads();
    for (int li = t; li < 64 * 64; li += 256) {
      int hd = li >> 6, d4 = (li & 63) * 4;
      float4 v = *reinterpret_cast<const float4*>(&Wq[(size_t)(rbase + hd) * 1024 + dt * 256 + d4]);
      Tq[(d4 + 0) * 64 + hd] = f2bf(v.x);
      Tq[(d4 + 1) * 64 + hd] = f2bf(v.y);
      Tq[(d4 + 2) * 64 + hd] = f2bf(v.z);
      Tq[(d4 + 3) * 64 + hd] = f2bf(v.w);
    }
    __syncthreads();
    f32x4 acc[4][4];
#pragma unroll
    for (int i = 0; i < 4; i++)
#pragma unroll
      for (int j = 0; j < 4; j++) acc[i][j] = (f32x4){0.f, 0.f, 0.f, 0.f};
#pragma unroll
    for (int kk = 0; kk < 2; ++kk) {
      bf16x8 af[4], bfr[4];
#pragma unroll
      for (int i = 0; i < 4; i++)
        af[i] = *reinterpret_cast<const bf16x8*>(&Ws[(i * 16 + lr) * 64 + kk * 32 + kg * 8]);
#pragma unroll
      for (int j = 0; j < 4; j++)
        bfr[j] = *reinterpret_cast<const bf16x8*>(&Tq[(w * 64 + j * 16 + lr) * 64 + kk * 32 + kg * 8]);
#pragma unroll
      for (int i = 0; i < 4; i++)
#pragma unroll
        for (int j = 0; j < 4; j++)
          acc[i][j] = __builtin_amdgcn_mfma_f32_16x16x32_bf16(af[i], bfr[j], acc[i][j], 0, 0, 0);
    }
#pragma unroll
    for (int i = 0; i < 4; i++)
#pragma unroll
      for (int j = 0; j < 4; j++)
#pragma unroll
        for (int r = 0; r < 4; r++)
          W3b[(size_t)(rbase + i * 16 + kg * 4 + r) * 1024 + dt * 256 + w * 64 + j * 16 + lr] =
              f2bf(acc[i][j][r]);
  }
}

// ---------------------------------------------------------------- kernel 2: 8-phase pipelined QKV GEMM + fused phi
// BM=BN=256, BK=64, 8 waves (2Mx4N, per-wave 128x64), 2-dbuf LDS (128 KB), 4 phases per
// K-tile x 16 MFMA, counted vmcnt(4) once per K-tile (never 0 mid-loop), raw barriers,
// conflict-free XOR chunk swizzle on both sides. Outputs:
//   phiQ -> [B,H,S,64] bf16,  phiK -> [B,H,64,S] bf16 (T),  V -> [B,H,64,S] bf16 (T)
__global__ __launch_bounds__(512, 2) void gemm_pipe_k(const ushort* __restrict__ xb,
                                                      const ushort* __restrict__ W3b,
                                                      const float* __restrict__ bias3,
                                                      ushort* __restrict__ Qb,
                                                      ushort* __restrict__ KTb,
                                                      ushort* __restrict__ VTb) {
  __shared__ __align__(16) ushort As[2 * 16384];   // [buf][256 rows][64 k] bf16, 64 KB
  __shared__ __align__(16) ushort Bs[2 * 16384];   // 64 KB
  const int t = threadIdx.x, wave = t >> 6, lane = t & 63;
  const int lr = lane & 15, kg = lane >> 4;
  const int wr = wave >> 2, wc = wave & 3;

  // XCD-bijective swizzle: 1536 = 8 * 192; each XCD: 16 m-tiles x 12 n-tiles, n fastest.
  const int flat = blockIdx.x;
  const int swz  = (flat & 7) * 192 + (flat >> 3);
  const int n0 = (swz % 12) * 256;
  const int m0 = (swz / 12) * 256;

  // Staging: half-tile = 128 rows x 64 cols = 2 gld_lds instrs (8 KB each).
  // HW writes lds base + lane*16B; lane l covers (row = w*8 + l>>3, chunkpos = l&7).
  // Swizzle: data at (row, pos) is global chunk g = pos ^ (row&7) => g = (l&7)^(l>>3).
  const int srow8 = wave * 8 + (lane >> 3);        // row within 64-row instr chunk
  const int sg    = (lane & 7) ^ (lane >> 3);      // global 8-elem col chunk
  const int swb   = wave * 512;                    // wave-uniform lds elem base

  auto stageA = [&](int tile, int buf, int h) {
    const int col = tile * 64 + sg * 8;
#pragma unroll
    for (int i2 = 0; i2 < 2; ++i2)
      gld_lds16(xb + (size_t)(m0 + h * 128 + i2 * 64 + srow8) * 1024 + col,
                As + buf * 16384 + h * 8192 + i2 * 4096 + swb);
  };
  auto stageB = [&](int tile, int buf, int h) {
    const int col = tile * 64 + sg * 8;
#pragma unroll
    for (int i2 = 0; i2 < 2; ++i2)
      gld_lds16(W3b + (size_t)(n0 + h * 128 + i2 * 64 + srow8) * 1024 + col,
                Bs + buf * 16384 + h * 8192 + i2 * 4096 + swb);
  };

  f32x4 acc[8][4];
#pragma unroll
  for (int f = 0; f < 8; f++)
#pragma unroll
    for (int j = 0; j < 4; j++) acc[f][j] = (f32x4){0.f, 0.f, 0.f, 0.f};

  // Read side: row bases are multiples of 16 => row&7 == lr&7. chunkpos = (kk*4+kg)^(lr&7)
  // gives exactly 2 lanes per bank-granule per instruction (free 2-way).
  auto readA4 = [&](int buf, int fh, int kk, bf16x8* a) {
#pragma unroll
    for (int f = 0; f < 4; f++) {
      const int row = wr * 128 + fh * 64 + f * 16 + lr;
      const int gp  = (kk * 4 + kg) ^ (lr & 7);
      a[f] = *reinterpret_cast<const bf16x8*>(As + buf * 16384 + row * 64 + gp * 8);
    }
  };
  auto readB4 = [&](int buf, int kk, bf16x8* b) {
#pragma unroll
    for (int j = 0; j < 4; j++) {
      const int row = wc * 64 + j * 16 + lr;
      const int gp  = (kk * 4 + kg) ^ (lr & 7);
      b[j] = *reinterpret_cast<const bf16x8*>(Bs + buf * 16384 + row * 64 + gp * 8);
    }
  };
  auto mfma16 = [&](const bf16x8* a, const bf16x8* b, int fh) {
    __builtin_amdgcn_s_setprio(1);
#pragma unroll
    for (int f = 0; f < 4; f++)
#pragma unroll
      for (int j = 0; j < 4; j++)
        acc[fh * 4 + f][j] =
            __builtin_amdgcn_mfma_f32_16x16x32_bf16(a[f], b[j], acc[fh * 4 + f][j], 0, 0, 0);
    __builtin_amdgcn_s_setprio(0);
  };

  // prologue: B(0), A(0), B(1) = 12 loads; wait so tile0 (oldest 8) landed, B(1) may fly.
  stageB(0, 0, 0); stageB(0, 0, 1);
  stageA(0, 0, 0); stageA(0, 0, 1);
  stageB(1, 1, 0); stageB(1, 1, 1);
  asm volatile("s_waitcnt vmcnt(4)" ::: "memory");
  BARF;

  bf16x8 a[4], b[4];
  // Per K-tile T (buf = T&1), 4 phases; stage schedule (write-safety derived):
  //  ph0: stage A-h0(T+1)->buf^1 | read B[kk0](4) + A[fh0][kk0](4) | MFMA 16
  //  ph1: stage A-h1(T+1)        | read A[fh1][kk0](4)             | MFMA 16
  //  ph2:                        | read B[kk1](4) + A[fh0][kk1](4) | MFMA 16
  //  ph3: stage B-h0,h1(T+2)->buf| read A[fh1][kk1](4)             | MFMA 16; vmcnt(W)
  auto TILE = [&](int T, int buf, bool stA, bool stB, int W) {
    // ph0
    if (stA) stageA(T + 1, buf ^ 1, 0);
    readB4(buf, 0, b);
    readA4(buf, 0, 0, a);
    BARF;
    mfma16(a, b, 0);
    BARF;
    // ph1
    if (stA) stageA(T + 1, buf ^ 1, 1);
    readA4(buf, 1, 0, a);
    BARF;
    mfma16(a, b, 1);
    BARF;
    // ph2
    readB4(buf, 1, b);
    readA4(buf, 0, 1, a);
    BARF;
    mfma16(a, b, 0);
    BARF;
    // ph3
    if (stB) { stageB(T + 2, buf, 0); stageB(T + 2, buf, 1); }
    readA4(buf, 1, 1, a);
    BARF;
    mfma16(a, b, 1);
    if (W == 4) asm volatile("s_waitcnt vmcnt(4)" ::: "memory");
    else        asm volatile("s_waitcnt vmcnt(0)" ::: "memory");
    BARF;
  };

#pragma unroll 1
  for (int tt = 0; tt < 8; ++tt) {
    const int T0 = tt * 2, T1 = T0 + 1;
    TILE(T0, 0, true,     T0 < 14, (T0 <= 13) ? 4 : 0);
    TILE(T1, 1, T1 < 15,  T1 < 14, (T1 <= 13) ? 4 : 0);
  }

  // epilogue: wave's 64 cols = one head of one part (n0 multiple of 256)
  const int n0w  = n0 + wc * 64;
  const int part = n0w >> 10;           // 0=phiQ 1=phiK(T) 2=V(T)
  const int h    = (n0w & 1023) >> 6;
  const int bq   = m0 >> 13;
  const int s_base = (m0 & 8191) + wr * 128;
  float bias[4];
#pragma unroll
  for (int j = 0; j < 4; j++) bias[j] = bias3[n0w + j * 16 + lr];

  if (part == 0) {
    ushort* dst = Qb + ((size_t)(bq * Hc + h)) * Sc * 64;
#pragma unroll
    for (int f = 0; f < 8; f++)
#pragma unroll
      for (int j = 0; j < 4; j++)
#pragma unroll
        for (int r = 0; r < 4; r++) {
          float p = acc[f][j][r] + bias[j];
          dst[(size_t)(s_base + f * 16 + kg * 4 + r) * 64 + j * 16 + lr] =
              f2bf(sqrtf(1.f + p * p));
        }
  } else {
    ushort* dst = ((part == 1) ? KTb : VTb) + ((size_t)(bq * Hc + h)) * 64 * Sc;
#pragma unroll
    for (int f = 0; f < 8; f++) {
      const int s = s_base + f * 16 + kg * 4;
#pragma unroll
      for (int j = 0; j < 4; j++) {
        ushort4 o;
        if (part == 1) {
#pragma unroll
          for (int r = 0; r < 4; r++) {
            float p = acc[f][j][r] + bias[j];
            (&o.x)[r] = f2bf(sqrtf(1.f + p * p));
          }
        } else {
#pragma unroll
          for (int r = 0; r < 4; r++) (&o.x)[r] = f2bf(acc[f][j][r] + bias[j]);
        }
        *reinterpret_cast<ushort4*>(&dst[(size_t)(j * 16 + lr) * Sc + s]) = o;
      }
    }
  }
}

// ---------------------------------------------------------------- kernel 3: KTV + ksum partials (T-layout inputs)
__global__ __launch_bounds__(256) void ktv_part_k(const ushort* __restrict__ KT,
                                                  const ushort* __restrict__ VT,
                                                  float* __restrict__ KTVp,
                                                  float* __restrict__ ksump) {
  __shared__ __align__(16) ushort Ks[64 * 128];
  __shared__ __align__(16) ushort Vs[64 * 128];
  __shared__ float red[64][65];
  const int t = threadIdx.x, chunk = blockIdx.x, bh = blockIdx.y;
  const int wave = t >> 6, lane = t & 63, lr = lane & 15, kg = lane >> 4;
  const size_t hb = (size_t)bh * 64 * Sc;
  const int s0 = chunk * 1024;

  f32x4 acc[4][4];
#pragma unroll
  for (int i = 0; i < 4; i++)
#pragma unroll
    for (int j = 0; j < 4; j++) acc[i][j] = (f32x4){0.f, 0.f, 0.f, 0.f};
  float ks_acc = 0.f;

  const int srl = t >> 4;
  const int scc = (t & 15) ^ ((t >> 4) & 7);
  const int wb  = (t >> 6) * 512;
  const int cR = ((wave * 4 + kg) ^ (lr & 7)) * 8;

  for (int st = 0; st < 8; ++st) {
    const int sb = s0 + st * 128;
    __syncthreads();
#pragma unroll
    for (int is = 0; is < 4; ++is) {
      const int row = is * 16 + srl;
      gld_lds16(KT + hb + (size_t)row * Sc + sb + scc * 8, Ks + is * 2048 + wb);
      gld_lds16(VT + hb + (size_t)row * Sc + sb + scc * 8, Vs + is * 2048 + wb);
    }
    __syncthreads();
    {
      bf16x8 af[4], bfr[4];
#pragma unroll
      for (int i = 0; i < 4; i++)
        af[i] = *reinterpret_cast<const bf16x8*>(&Ks[(i * 16 + lr) * 128 + cR]);
#pragma unroll
      for (int j = 0; j < 4; j++)
        bfr[j] = *reinterpret_cast<const bf16x8*>(&Vs[(j * 16 + lr) * 128 + cR]);
#pragma unroll
      for (int i = 0; i < 4; i++)
#pragma unroll
        for (int j = 0; j < 4; j++)
          acc[i][j] = __builtin_amdgcn_mfma_f32_16x16x32_bf16(af[i], bfr[j], acc[i][j], 0, 0, 0);
    }
    if (t < 64) {
      float s = 0.f;
      for (int e = 0; e < 128; e++) s += bf2f(Ks[t * 128 + e]);
      ks_acc += s;
    }
  }

  __syncthreads();
  for (int li = t; li < 64 * 65; li += 256) (&red[0][0])[li] = 0.f;
  __syncthreads();
  for (int w = 0; w < 4; w++) {
    if (wave == w) {
#pragma unroll
      for (int i = 0; i < 4; i++)
#pragma unroll
        for (int j = 0; j < 4; j++)
#pragma unroll
          for (int r = 0; r < 4; r++)
            red[i * 16 + kg * 4 + r][j * 16 + lr] += acc[i][j][r];
    }
    __syncthreads();
  }
  float* outp = KTVp + ((size_t)bh * 8 + chunk) * 4096;
  for (int li = t; li < 4096; li += 256) outp[li] = red[li >> 6][li & 63];
  if (t < 64) ksump[((size_t)bh * 8 + chunk) * 64 + t] = ks_acc;
}

// ---------------------------------------------------------------- kernel 3b: reduce partials
__global__ __launch_bounds__(256) void ktv_red_k(const float* __restrict__ KTVp,
                                                 const float* __restrict__ ksump,
                                                 float* __restrict__ KTV,
                                                 float* __restrict__ ksum) {
  const int bh = blockIdx.x, t = threadIdx.x;
  for (int li = t; li < 4096; li += 256) {
    float s = 0.f;
    for (int c = 0; c < 8; c++) s += KTVp[((size_t)bh * 8 + c) * 4096 + li];
    KTV[(size_t)bh * 4096 + li] = s;
  }
  if (t < 64) {
    float s = 0.f;
    for (int c = 0; c < 8; c++) s += ksump[((size_t)bh * 8 + c) * 64 + t];
    ksum[bh * 64 + t] = s;
  }
}

// ---------------------------------------------------------------- kernel 4: numerator + denominator + output
__global__ __launch_bounds__(256) void out_k(const ushort* __restrict__ Qphi,
                                             const float* __restrict__ KTV,
                                             const float* __restrict__ ksum,
                                             float* __restrict__ out) {
  __shared__ ushort Qs[256][72];
  __shared__ ushort BT[64][72];     // KTV^T in bf16: BT[v][a]
  __shared__ float  den[256];
  __shared__ float  kss[64];
  const int t = threadIdx.x;
  const int bh = blockIdx.y, s0 = blockIdx.x * 256;
  const ushort* qb = Qphi + (size_t)bh * Sc * 64 + (size_t)s0 * 64;

#pragma unroll
  for (int i = 0; i < 8; i++) {
    int li = i * 256 + t;
    int r = li >> 3, c8 = li & 7;
    *reinterpret_cast<uint4*>(&Qs[r][c8 * 8]) = *reinterpret_cast<const uint4*>(&qb[li * 8]);
  }
  for (int li = t; li < 4096; li += 256) {
    int a = li >> 6, v = li & 63;
    BT[v][a] = f2bf(KTV[(size_t)bh * 4096 + li]);
  }
  if (t < 64) kss[t] = ksum[bh * 64 + t];
  __syncthreads();

  {
    float d = 0.f;
    for (int a = 0; a < 64; a++) d += bf2f(Qs[t][a]) * kss[a];
    den[t] = d + EPSc;
  }
  __syncthreads();

  const int wave = t >> 6, lane = t & 63, lr = lane & 15, kg = lane >> 4;
  f32x4 acc[4][4];
#pragma unroll
  for (int i = 0; i < 4; i++)
#pragma unroll
    for (int j = 0; j < 4; j++) acc[i][j] = (f32x4){0.f, 0.f, 0.f, 0.f};

#pragma unroll
  for (int ks = 0; ks < 64; ks += 32) {
    bf16x8 af[4], bfr[4];
#pragma unroll
    for (int i = 0; i < 4; i++)
      af[i] = *reinterpret_cast<const bf16x8*>(&Qs[wave * 64 + i * 16 + lr][ks + kg * 8]);
#pragma unroll
    for (int j = 0; j < 4; j++)
      bfr[j] = *reinterpret_cast<const bf16x8*>(&BT[j * 16 + lr][ks + kg * 8]);
#pragma unroll
    for (int i = 0; i < 4; i++)
#pragma unroll
      for (int j = 0; j < 4; j++)
        acc[i][j] = __builtin_amdgcn_mfma_f32_16x16x32_bf16(af[i], bfr[j], acc[i][j], 0, 0, 0);
  }

  const int bq = bh >> 4, h = bh & 15;
#pragma unroll
  for (int i = 0; i < 4; i++) {
#pragma unroll
    for (int j = 0; j < 4; j++) {
#pragma unroll
      for (int r = 0; r < 4; r++) {
        int row = wave * 64 + i * 16 + kg * 4 + r;
        int s = s0 + row;
        int v = j * 16 + lr;
        out[((size_t)bq * Sc + s) * 1024 + h * 64 + v] = acc[i][j][r] / den[row];
      }
    }
  }
}

// ---------------------------------------------------------------- launch
extern "C" void kernel_launch(void* const* d_in, const int* in_sizes, int n_in,
                              void* d_out, int out_size, void* d_ws, size_t ws_size,
                              hipStream_t stream) {
  const float* x     = (const float*)d_in[0];
  const float* W_qkv = (const float*)d_in[1];
  const float* b_qkv = (const float*)d_in[2];
  const float* W_p   = (const float*)d_in[3];
  const float* b_p   = (const float*)d_in[4];
  float* out = (float*)d_out;

  size_t off = 0;
  auto carve = [&](size_t bytes) -> void* {
    void* p = (char*)d_ws + off;
    off += (bytes + 255) & ~(size_t)255;
    return p;
  };
  const size_t headElems = (size_t)BHc * Sc * 64;           // 33,554,432
  ushort* xb    = (ushort*)carve((size_t)Mc * Dc * 2);      // 64 MB
  ushort* Qb    = (ushort*)carve(headElems * 2);            // phiQ  [B,H,S,64]
  ushort* KTb   = (ushort*)carve(headElems * 2);            // phiK  [B,H,64,S]
  ushort* VTb   = (ushort*)carve(headElems * 2);            // V     [B,H,64,S]
  ushort* W3b   = (ushort*)carve((size_t)N3c * Dc * 2);
  float*  bias3 = (float*)carve((size_t)N3c * 4);
  float*  KTVp  = (float*)carve((size_t)BHc * 8 * 4096 * 4);
  float*  ksmp  = (float*)carve((size_t)BHc * 8 * 64 * 4);
  float*  KTV   = (float*)carve((size_t)BHc * 4096 * 4);
  float*  ksum  = (float*)carve((size_t)BHc * 64 * 4);
  (void)ws_size; (void)n_in; (void)in_sizes; (void)out_size;

  cvt_bf16_k<<<2048, 256, 0, stream>>>(x, xb, Mc * Dc / 4);
  fold_k<<<48, 256, 0, stream>>>(W_qkv, W_p, b_qkv, b_p, W3b, bias3);
  gemm_pipe_k<<<(Mc / 256) * (N3c / 256), 512, 0, stream>>>(xb, W3b, bias3, Qb, KTb, VTb);
  ktv_part_k<<<dim3(8, BHc), 256, 0, stream>>>(KTb, VTb, KTVp, ksmp);
  ktv_red_k<<<BHc, 256, 0, stream>>>(KTVp, ksmp, KTV, ksum);
  out_k<<<dim3(Sc / 256, BHc), 256, 0, stream>>>(Qb, KTV, ksum, out);
}